// Round 17
// baseline (270.927 us; speedup 1.0000x reference)
//
#include <hip/hip_runtime.h>
#include <hip/hip_bf16.h>
#include <math.h>
#include <string.h>

#define B_    2
#define C_    1536
#define S_    16384
#define H_    768
#define T_    367
#define P_    128
#define HALF_ 384
#define TT_   734                 // 2*T
#define NT2_  184                 // ceil(T/2) t-pairs
#define PRED_ELEMS 24051712      // B*P*P*2T

// ws layout (float slots)
#define XHH_OFF  0               // 786,432 ushorts = 393,216 f32 slots
#define CSH_OFF  393216          // 786,432 ushorts
#define INVF_OFF 786432          // 384 doubles (768 slots)
#define XCB_OFF  787200          // [B*4*P][C] bf16 = 1,572,864 ushorts
#define W1WS_OFF 1573632         // optional w1 staging: 4*T*P*P bf16 = 48.1 MB

typedef short short8 __attribute__((ext_vector_type(8)));
typedef _Float16 f16x8 __attribute__((ext_vector_type(8)));
typedef _Float16 h2    __attribute__((ext_vector_type(2)));
typedef float f32x4  __attribute__((ext_vector_type(4)));

__device__ __forceinline__ unsigned int packbf2(float a, float b) {
    __hip_bfloat162 h = __float22bfloat162_rn(make_float2(a, b));
    unsigned int r; __builtin_memcpy(&r, &h, 4); return r;
}
__device__ __forceinline__ unsigned short packbf1(float a) {
    __hip_bfloat16 h = __float2bfloat16(a);
    unsigned short r; __builtin_memcpy(&r, &h, 2); return r;
}
__device__ __forceinline__ unsigned short f2h(float x) {
    _Float16 h = (_Float16)x;
    unsigned short r; __builtin_memcpy(&r, &h, 2); return r;
}
__device__ __forceinline__ h2 bch(unsigned int v) { h2 r; __builtin_memcpy(&r, &v, 4); return r; }
__device__ __forceinline__ unsigned int hcb(h2 v) { unsigned int r; __builtin_memcpy(&r, &v, 4); return r; }

// ---------------- A0: gather embedding columns -> bf16 ----------------
__global__ void gather_cols(const float* __restrict__ emb,
                            const int* __restrict__ sp,
                            unsigned short* __restrict__ xcb) {
    int blk = blockIdx.x;           // B*4*P = 1024
    int p = blk & 127;
    int g = (blk >> 7) & 3;
    int b = blk >> 9;
    int s = sp[(b * 4 + g) * P_ + p];
    const float* src = emb + (size_t)b * C_ * S_ + s;
    unsigned short* dst = xcb + ((size_t)(b * 4 + g) * P_ + p) * C_;
    for (int c = threadIdx.x; c < C_; c += blockDim.x)
        dst[c] = packbf1(src[(size_t)c * S_]);
}

// ---------------- A1: gathered-logits GEMM via bf16 MFMA, 64x64 tiles ----------------
// writes xhh as packed-f16 granules: idx = r*768 + (hj>>2)*8 + sel*4 + (hj&3)
__global__ __launch_bounds__(256) void logits_mfma(
    const unsigned short* __restrict__ xcb, const float* __restrict__ w,
    const float* __restrict__ bias, const int* __restrict__ org,
    unsigned short* __restrict__ xhh) {
    __shared__ __align__(16) unsigned short tX[64 * 64];   // 8KB
    __shared__ __align__(16) unsigned short tW[64 * 64];   // 8KB
    int mt = blockIdx.x;             // 0..15 (rows of 64)
    int nt = blockIdx.y;             // 0..11 (cols of 64)
    int o = org[mt >> 3];
    int r0 = mt * 64, h0 = nt * 64;
    int tid = threadIdx.x;
    int lane = tid & 63, wid = tid >> 6;
    int wrow = (wid >> 1) * 32, wcol = (wid & 1) * 32;
    int lr = lane & 15, lq = lane >> 4;
    int gr0 = (lq ^ (lr & 7)) * 8;

    f32x4 acc[2][2];
    #pragma unroll
    for (int i = 0; i < 2; ++i)
        #pragma unroll
        for (int j = 0; j < 2; ++j) acc[i][j] = (f32x4){0.f, 0.f, 0.f, 0.f};

    int srow = tid >> 2, sg = tid & 3;   // staging: 4 thr/row, 2 granules each

    for (int kc = 0; kc < C_; kc += 64) {
        if (kc) __syncthreads();
        {   // stage X (bf16 direct)
            const unsigned short* src = xcb + (size_t)(r0 + srow) * C_ + kc;
            unsigned short* drow = tX + srow * 64;
            #pragma unroll
            for (int i = 0; i < 2; ++i) {
                int g = sg + i * 4;
                uint4 v = *(const uint4*)(src + g * 8);
                *(uint4*)&drow[(g ^ (srow & 7)) * 8] = v;
            }
        }
        {   // stage W (f32 -> bf16)
            const float* srcw = w + ((size_t)o * H_ + h0 + srow) * C_ + kc;
            unsigned short* drow = tW + srow * 64;
            #pragma unroll
            for (int i = 0; i < 2; ++i) {
                int g = sg + i * 4;
                float4 v0 = *(const float4*)(srcw + g * 8);
                float4 v1 = *(const float4*)(srcw + g * 8 + 4);
                uint4 pk;
                pk.x = packbf2(v0.x, v0.y); pk.y = packbf2(v0.z, v0.w);
                pk.z = packbf2(v1.x, v1.y); pk.w = packbf2(v1.z, v1.w);
                *(uint4*)&drow[(g ^ (srow & 7)) * 8] = pk;
            }
        }
        __syncthreads();
        #pragma unroll
        for (int kk = 0; kk < 64; kk += 32) {
            short8 af[2], bf2[2];
            #pragma unroll
            for (int fi = 0; fi < 2; ++fi)
                af[fi] = *(const short8*)&tX[(wrow + fi * 16 + lr) * 64 + (gr0 ^ kk)];
            #pragma unroll
            for (int fj = 0; fj < 2; ++fj)
                bf2[fj] = *(const short8*)&tW[(wcol + fj * 16 + lr) * 64 + (gr0 ^ kk)];
            #pragma unroll
            for (int fi = 0; fi < 2; ++fi)
                #pragma unroll
                for (int fj = 0; fj < 2; ++fj)
                    acc[fi][fj] = __builtin_amdgcn_mfma_f32_16x16x32_bf16(
                        af[fi], bf2[fj], acc[fi][fj], 0, 0, 0);
        }
    }
    #pragma unroll
    for (int fi = 0; fi < 2; ++fi)
        #pragma unroll
        for (int rr = 0; rr < 4; ++rr) {
            int r = r0 + wrow + fi * 16 + lq * 4 + rr;
            #pragma unroll
            for (int fj = 0; fj < 2; ++fj) {
                int h = h0 + wcol + fj * 16 + lr;
                int hj = (h < HALF_) ? h : (h - HALF_);
                int sel = (h < HALF_) ? 0 : 1;
                xhh[(size_t)r * H_ + (hj >> 2) * 8 + sel * 4 + (hj & 3)] =
                    f2h(acc[fi][fj][rr] + bias[o * H_ + h]);
            }
        }
}

// ---------------- A2a: inv-freq table (fp64) ----------------
__global__ void init_invf(double* __restrict__ invf) {
    int j = threadIdx.x;
    if (j < HALF_) invf[j] = exp2(-20.0 * (double)j / 384.0);
}

// ---------------- A2b: RoPE cos/sin table, packed-f16 granules {c x4}{s x4} ----------------
__global__ void rope_table(const int* __restrict__ sp,
                           const double* __restrict__ invf,
                           unsigned short* __restrict__ csh) {
    int e = blockIdx.x * blockDim.x + threadIdx.x;  // 1024*384
    if (e >= B_ * 4 * P_ * HALF_) return;
    int j = e % HALF_;
    int r = e / HALF_;
    int s = sp[r];
    const double TWO_PI = 6.283185307179586476925286766559;
    double ang = (double)s * invf[j];
    double k = rint(ang * (1.0 / TWO_PI));
    float fr = (float)(ang - k * TWO_PI);
    float sv, cv;
    __sincosf(fr, &sv, &cv);
    int base = r * H_ + (j >> 2) * 8 + (j & 3);
    csh[base]     = f2h(cv);
    csh[base + 4] = f2h(sv);
}

// one rope+affine build: inputs packed-f16 granule regs, coef LDS base
#define BUILD4(cof, xv, cAh, cBh, sAh, sBh, dst)                               \
    {                                                                          \
        uint4 sc = *(const uint4*)((cof) + kb);                                \
        uint4 of = *(const uint4*)((cof) + 768 + kb);                          \
        h2 u1a = __builtin_elementwise_fma(bch(sc.x), bch((xv).x), bch(of.x)); \
        h2 u1b = __builtin_elementwise_fma(bch(sc.y), bch((xv).y), bch(of.y)); \
        h2 u2a = __builtin_elementwise_fma(bch(sc.z), bch((xv).z), bch(of.z)); \
        h2 u2b = __builtin_elementwise_fma(bch(sc.w), bch((xv).w), bch(of.w)); \
        uint4 wv;                                                              \
        wv.x = hcb(__builtin_elementwise_fma(u1a, (cAh), -(u2a * (sAh))));     \
        wv.y = hcb(__builtin_elementwise_fma(u1b, (cBh), -(u2b * (sBh))));     \
        wv.z = hcb(__builtin_elementwise_fma(u1a, (sAh), u2a * (cAh)));        \
        wv.w = hcb(__builtin_elementwise_fma(u1b, (sBh), u2b * (cBh)));        \
        *(uint4*)&(dst) = wv;                                                  \
    }

// ---------------- B: junction GEMM via f16 MFMA, 2 t per block ----------------
// R17: K-chunk 32, D and A merged into one 128B row [D g0-3 | A g4-7] with
// full 8-slot XOR swizzle (row width stays 128B -> conflict-free, unlike
// R6's 64B rows). LDS: 2buf x 2t x 128 x 64 ushorts = 64KB + 12KB coefs
// -> 77KB -> 2 blocks/CU = 32 waves/CU, TWO barrier groups (R16 lesson:
// 1 lockstep group can't hide ~14 barrier drains). Per-thread VALU/LDS/VMEM
// totals identical to R16; only granularity + residency change.
// 16 waves = 2t x 8, wave = 64x32 of its t. 1 barrier/chunk, 24 chunks.
// (1024,8): VGPR cap 64 (R16 measured 60 with MORE live state); a spill
// shows as WRITE_SIZE blowup -> rollback trigger.
__global__ __launch_bounds__(1024, 8) void junction_mfma(
    const unsigned short* __restrict__ xhh, const unsigned short* __restrict__ csh,
    const float* __restrict__ rpd, const float* __restrict__ rpa,
    const float* __restrict__ rnd, const float* __restrict__ rna,
    const int* __restrict__ org, const int* __restrict__ sp,
    unsigned short* __restrict__ w1) {
    __shared__ __align__(16) unsigned short smem[32768];   // 64KB: [buf2][t2][128*64]
    __shared__ __align__(16) unsigned short scofh[6144];   // 12KB: [t][side][sc|of][768]
    __shared__ int vD[P_], vA[P_];

    // bijective XCD swizzle (nwg = 736, %8 == 0)
    int nwg = gridDim.x;
    int orig = blockIdx.x;
    int xcd = orig & 7;
    int q = nwg >> 3, r8 = nwg & 7;
    int blk = (xcd < r8 ? xcd * (q + 1) : r8 * (q + 1) + (xcd - r8) * q) + (orig >> 3);

    int tp = blk % NT2_;
    int sign = (blk / NT2_) & 1;
    int b = blk / (2 * NT2_);
    int o = org[b];
    int t0 = 2 * tp, t1 = t0 + 1;
    int t1ok = (t1 < T_);
    int t1c = t1ok ? t1 : t0;       // clamped for coef reads
    int gd = sign * 2, ga = sign * 2 + 1;
    const float* pd = sign ? rnd : rpd;
    const float* pa = sign ? rna : rpa;
    int tid = threadIdx.x;

    // stage coefs for both t, f16, granule layout {s1 x4}{s2 x4}
    for (int e = tid; e < 6144; e += 1024) {
        int tsel_ = e / 3072;
        int rem = e - tsel_ * 3072;
        int side_ = rem / 1536;
        int rem2 = rem - side_ * 1536;
        int arr = rem2 / 768;              // 0 = scale, 1 = offset
        int e2 = rem2 - arr * 768;
        int tt = tsel_ ? t1c : t0;
        const float* base = (side_ ? pa : pd) + ((size_t)(o * 2 + arr) * T_ + tt) * H_;
        int hj = (e2 < HALF_) ? e2 : (e2 - HALF_);
        int sel = (e2 < HALF_) ? 0 : 1;
        int pos = (hj >> 2) * 8 + sel * 4 + (hj & 3);
        scofh[((tsel_ * 2 + side_) * 2 + arr) * 768 + pos] = f2h(base[e2]);
    }
    if (tid < P_) {
        vD[tid] = sp[(b * 4 + gd) * P_ + tid] >= 0;
        vA[tid] = sp[(b * 4 + ga) * P_ + tid] >= 0;
    }
    const unsigned short* xdh = xhh + ((size_t)(b * 4 + gd) * P_) * H_;
    const unsigned short* xah = xhh + ((size_t)(b * 4 + ga) * P_) * H_;
    const unsigned short* cdh = csh + ((size_t)(b * 4 + gd) * P_) * H_;
    const unsigned short* cah = csh + ((size_t)(b * 4 + ga) * P_) * H_;

    int lane = tid & 63, wid = tid >> 6;            // wid 0..15
    int tsel = wid >> 3;                            // which t this wave computes
    int w8 = wid & 7;
    int wrow = (w8 >> 2) * 64, wcol = (w8 & 3) * 32;
    int lr = lane & 15, lq = lane >> 4;
    int grA = (lq ^ (lr & 7)) << 3;   // D-granule byte-slot; A = grA ^ 32

    f32x4 acc[4][2];
    #pragma unroll
    for (int i = 0; i < 4; ++i)
        #pragma unroll
        for (int j = 0; j < 2; ++j) acc[i][j] = (f32x4){0.f, 0.f, 0.f, 0.f};

    // build mapping: thread owns (prow, g); g<4 = D granule g, g>=4 = A granule g-4
    int prow = tid >> 3, g = tid & 7;
    int side = g >> 2, gc = g & 3;
    const unsigned short* x_t = (side ? xah : xdh) + prow * H_ + gc * 8;
    const unsigned short* c_t = (side ? cah : cdh) + prow * H_ + gc * 8;
    int sw = prow * 64 + ((g ^ (prow & 7)) << 3);
    const unsigned short* cof0 = scofh + side * 1536;          // t0 this side
    const unsigned short* cof1 = scofh + 3072 + side * 1536;   // t1 this side

    // prefetch ch=0 (2 x 16B)
    uint4 pxv = *(const uint4*)x_t;
    uint4 pcv = *(const uint4*)c_t;

    __syncthreads();          // scofh / vD / vA ready

    for (int ch = 0; ch < 24; ++ch) {
        unsigned short* bufb = smem + (ch & 1) * 16384;
        int kb = (ch * 4 + gc) * 8;

        {
            h2 cA = bch(pcv.x), cB = bch(pcv.y), sA = bch(pcv.z), sB = bch(pcv.w);
            BUILD4(cof0, pxv, cA, cB, sA, sB, bufb[sw]);           // t0
            BUILD4(cof1, pxv, cA, cB, sA, sB, bufb[8192 + sw]);    // t1
        }
        if (ch < 23) {   // next chunk's loads; latency covered by bar+MFMA
            int o2 = (ch + 1) * 32;
            pxv = *(const uint4*)(x_t + o2);
            pcv = *(const uint4*)(c_t + o2);
        }
        __syncthreads();

        __builtin_amdgcn_s_setprio(1);
        {
            const unsigned short* tb = bufb + tsel * 8192;
            f16x8 af[4], bf2[2];
            #pragma unroll
            for (int fi = 0; fi < 4; ++fi)
                af[fi] = *(const f16x8*)&tb[(wrow + fi * 16 + lr) * 64 + grA];
            #pragma unroll
            for (int fj = 0; fj < 2; ++fj)
                bf2[fj] = *(const f16x8*)&tb[(wcol + fj * 16 + lr) * 64 + (grA ^ 32)];
            #pragma unroll
            for (int fi = 0; fi < 4; ++fi)
                #pragma unroll
                for (int fj = 0; fj < 2; ++fj)
                    acc[fi][fj] = __builtin_amdgcn_mfma_f32_16x16x32_f16(
                        af[fi], bf2[fj], acc[fi][fj], 0, 0, 0);
        }
        __builtin_amdgcn_s_setprio(0);
    }

    // ---- epilogue: stage both t tiles across the whole 64KB smem ----
    __syncthreads();   // all mfma(23) reads done; entire smem free
    #pragma unroll
    for (int fi = 0; fi < 4; ++fi) {
        #pragma unroll
        for (int rr = 0; rr < 4; ++rr) {
            int d = wrow + fi * 16 + lq * 4 + rr;
            int vd = vD[d];
            #pragma unroll
            for (int fj = 0; fj < 2; ++fj) {
                int a = wcol + fj * 16 + lr;
                float x = acc[fi][fj][rr];
                float v = 0.0f;
                if (vd && vA[a]) v = (x > 15.0f) ? x : __logf(1.0f + __expf(x));
                smem[tsel * 16384 + d * P_ + a] = packbf1(v);
            }
        }
    }
    __syncthreads();
    const uint4* s4 = (const uint4*)smem;
    uint4* d40 = (uint4*)(w1 + (size_t)((b * 2 + sign) * T_ + t0) * (P_ * P_));
    for (int i = tid; i < 2048; i += 1024) d40[i] = s4[i];
    if (t1ok) {
        uint4* d41 = (uint4*)(w1 + (size_t)((b * 2 + sign) * T_ + t1) * (P_ * P_));
        for (int i = tid; i < 2048; i += 1024) d41[i] = s4[2048 + i];
    }
}

// ---------------- C (ws path): fused transpose + mask (w1 in d_ws, no alias) ----------------
__global__ __launch_bounds__(256) void finalize_ws(const __hip_bfloat16* __restrict__ w1,
                                                   const int* __restrict__ sp,
                                                   float* __restrict__ pred,
                                                   float* __restrict__ mask) {
    __shared__ float tile[64 * 129];
    __shared__ float mval[P_];
    int blk = blockIdx.x;            // bs*128*6 + d*6 + tt   (3072 blocks)
    int tt = blk % 6;
    int d = (blk / 6) % P_;
    int bs = blk / (6 * P_);         // b*2+sign
    int b = bs >> 1, sign = bs & 1;
    int t0 = tt * 64;
    int tcnt = min(64, T_ - t0);
    int tid = threadIdx.x;

    const __hip_bfloat16* src = w1 + (size_t)bs * T_ * P_ * P_ + (size_t)d * P_;
    for (int e = tid; e < tcnt * P_; e += 256) {
        int i = e >> 7, a = e & 127;
        tile[i * 129 + a] = __bfloat162float(src[(size_t)(t0 + i) * P_ * P_ + a]);
    }
    if (tid < P_) {
        bool vd = sp[(b * 4 + sign * 2) * P_ + d] >= 0;
        bool va = sp[(b * 4 + sign * 2 + 1) * P_ + tid] >= 0;
        mval[tid] = (vd && va) ? 1.0f : 0.0f;
    }
    __syncthreads();
    size_t obase = ((size_t)(b * P_ + d) * P_) * TT_ + sign * T_ + t0;
    float* dstp = pred + obase;
    float* dstm = mask + obase;
    for (int e = tid; e < P_ * 64; e += 256) {
        int a = e >> 6, ii = e & 63;
        if (ii < tcnt) {
            dstp[(size_t)a * TT_ + ii] = tile[ii * 129 + a];
            dstm[(size_t)a * TT_ + ii] = mval[a];
        }
    }
}

// ---------------- C' (fallback): transpose only; w1 aliases mask half ----------------
__global__ __launch_bounds__(256) void transpose_out(const __hip_bfloat16* __restrict__ w1,
                                                     float* __restrict__ pred) {
    __shared__ float tile[64 * 129];
    int blk = blockIdx.x;
    int tt = blk % 6;
    int d = (blk / 6) % P_;
    int bs = blk / (6 * P_);
    int b = bs >> 1, sign = bs & 1;
    int t0 = tt * 64;
    int tcnt = min(64, T_ - t0);
    int tid = threadIdx.x;

    const __hip_bfloat16* src = w1 + (size_t)bs * T_ * P_ * P_ + (size_t)d * P_;
    for (int e = tid; e < tcnt * P_; e += 256) {
        int i = e >> 7, a = e & 127;
        tile[i * 129 + a] = __bfloat162float(src[(size_t)(t0 + i) * P_ * P_ + a]);
    }
    __syncthreads();
    float* dst = pred + ((size_t)(b * P_ + d) * P_) * TT_ + sign * T_ + t0;
    for (int e = tid; e < P_ * 64; e += 256) {
        int a = e >> 6, ii = e & 63;
        if (ii < tcnt) dst[(size_t)a * TT_ + ii] = tile[ii * 129 + a];
    }
}

// ---------------- D' (fallback): mask fill, MUST follow transpose_out ----------------
__global__ void mask_fill(const int* __restrict__ sp, float* __restrict__ mask) {
    int blk = blockIdx.x;
    int a = blk & 127;
    int d = (blk >> 7) & 127;
    int b = blk >> 14;
    bool vp = (sp[(b * 4 + 0) * P_ + d] >= 0) && (sp[(b * 4 + 1) * P_ + a] >= 0);
    bool vn = (sp[(b * 4 + 2) * P_ + d] >= 0) && (sp[(b * 4 + 3) * P_ + a] >= 0);
    float* dst = mask + (size_t)blk * TT_;
    for (int st = threadIdx.x; st < TT_; st += blockDim.x)
        dst[st] = (st < T_ ? vp : vn) ? 1.0f : 0.0f;
}

extern "C" void kernel_launch(void* const* d_in, const int* in_sizes, int n_in,
                              void* d_out, int out_size, void* d_ws, size_t ws_size,
                              hipStream_t stream) {
    const float* emb  = (const float*)d_in[0];
    const float* w    = (const float*)d_in[1];
    const float* bias = (const float*)d_in[2];
    const float* rpd  = (const float*)d_in[3];
    const float* rpa  = (const float*)d_in[4];
    const float* rnd  = (const float*)d_in[5];
    const float* rna  = (const float*)d_in[6];
    const int*   org  = (const int*)d_in[7];
    const int*   sp   = (const int*)d_in[8];

    float* out = (float*)d_out;
    float* ws  = (float*)d_ws;
    unsigned short* xhh = (unsigned short*)(ws + XHH_OFF);
    unsigned short* csh = (unsigned short*)(ws + CSH_OFF);
    double* invf = (double*)(ws + INVF_OFF);
    unsigned short* xcb = (unsigned short*)(ws + XCB_OFF);
    float* pred  = out;
    float* maskp = out + PRED_ELEMS;

    // w1 staging: prefer d_ws (enables fused finalize without the R12 alias
    // race); fall back to the mask half of d_out (then mask_fill must follow
    // transpose_out in stream order).
    size_t w1_bytes = (size_t)4 * T_ * P_ * P_ * 2;
    size_t need = (size_t)W1WS_OFF * 4 + w1_bytes;
    bool ws_ok = (ws_size >= need);
    unsigned short* w1 = ws_ok ? (unsigned short*)(ws + W1WS_OFF)
                               : (unsigned short*)maskp;

    init_invf<<<1, 384, 0, stream>>>(invf);
    gather_cols<<<1024, 256, 0, stream>>>(emb, sp, xcb);
    rope_table<<<1536, 256, 0, stream>>>(sp, invf, csh);
    dim3 gl(16, 12);
    logits_mfma<<<gl, 256, 0, stream>>>(xcb, w, bias, org, xhh);
    junction_mfma<<<2 * 2 * NT2_, 1024, 0, stream>>>(xhh, csh, rpd, rpa, rnd, rna, org, sp, w1);
    if (ws_ok) {
        finalize_ws<<<2 * 2 * P_ * 6, 256, 0, stream>>>((const __hip_bfloat16*)w1, sp, pred, maskp);
    } else {
        transpose_out<<<2 * 2 * P_ * 6, 256, 0, stream>>>((const __hip_bfloat16*)w1, pred);
        mask_fill<<<32768, 256, 0, stream>>>(sp, maskp);
    }
}

// Round 18
// 228.099 us; speedup vs baseline: 1.1878x; 1.1878x over previous
//
#include <hip/hip_runtime.h>
#include <hip/hip_bf16.h>
#include <math.h>
#include <string.h>

#define B_    2
#define C_    1536
#define S_    16384
#define H_    768
#define T_    367
#define P_    128
#define HALF_ 384
#define TT_   734                 // 2*T
#define NT2_  184                 // ceil(T/2) t-pairs
#define PRED_ELEMS 24051712      // B*P*P*2T

// ws layout (float slots)
#define XHH_OFF  0               // 786,432 ushorts = 393,216 f32 slots
#define CSH_OFF  393216          // 786,432 ushorts
#define INVF_OFF 786432          // 384 doubles (768 slots)
#define XCB_OFF  787200          // [B*4*P][C] bf16 = 1,572,864 ushorts
#define W1WS_OFF 1573632         // optional w1 staging: 4*T*P*P bf16 = 48.1 MB

typedef short short8 __attribute__((ext_vector_type(8)));
typedef _Float16 f16x8 __attribute__((ext_vector_type(8)));
typedef _Float16 h2    __attribute__((ext_vector_type(2)));
typedef float f32x4  __attribute__((ext_vector_type(4)));

__device__ __forceinline__ unsigned int packbf2(float a, float b) {
    __hip_bfloat162 h = __float22bfloat162_rn(make_float2(a, b));
    unsigned int r; __builtin_memcpy(&r, &h, 4); return r;
}
__device__ __forceinline__ unsigned short packbf1(float a) {
    __hip_bfloat16 h = __float2bfloat16(a);
    unsigned short r; __builtin_memcpy(&r, &h, 2); return r;
}
__device__ __forceinline__ unsigned short f2h(float x) {
    _Float16 h = (_Float16)x;
    unsigned short r; __builtin_memcpy(&r, &h, 2); return r;
}
__device__ __forceinline__ h2 bch(unsigned int v) { h2 r; __builtin_memcpy(&r, &v, 4); return r; }
__device__ __forceinline__ unsigned int hcb(h2 v) { unsigned int r; __builtin_memcpy(&r, &v, 4); return r; }

// ---------------- A0: gather embedding columns -> bf16 ----------------
__global__ void gather_cols(const float* __restrict__ emb,
                            const int* __restrict__ sp,
                            unsigned short* __restrict__ xcb) {
    int blk = blockIdx.x;           // B*4*P = 1024
    int p = blk & 127;
    int g = (blk >> 7) & 3;
    int b = blk >> 9;
    int s = sp[(b * 4 + g) * P_ + p];
    const float* src = emb + (size_t)b * C_ * S_ + s;
    unsigned short* dst = xcb + ((size_t)(b * 4 + g) * P_ + p) * C_;
    for (int c = threadIdx.x; c < C_; c += blockDim.x)
        dst[c] = packbf1(src[(size_t)c * S_]);
}

// ---------------- A1: gathered-logits GEMM via bf16 MFMA, 64x64 tiles ----------------
// writes xhh as packed-f16 granules: idx = r*768 + (hj>>2)*8 + sel*4 + (hj&3)
__global__ __launch_bounds__(256) void logits_mfma(
    const unsigned short* __restrict__ xcb, const float* __restrict__ w,
    const float* __restrict__ bias, const int* __restrict__ org,
    unsigned short* __restrict__ xhh) {
    __shared__ __align__(16) unsigned short tX[64 * 64];   // 8KB
    __shared__ __align__(16) unsigned short tW[64 * 64];   // 8KB
    int mt = blockIdx.x;             // 0..15 (rows of 64)
    int nt = blockIdx.y;             // 0..11 (cols of 64)
    int o = org[mt >> 3];
    int r0 = mt * 64, h0 = nt * 64;
    int tid = threadIdx.x;
    int lane = tid & 63, wid = tid >> 6;
    int wrow = (wid >> 1) * 32, wcol = (wid & 1) * 32;
    int lr = lane & 15, lq = lane >> 4;
    int gr0 = (lq ^ (lr & 7)) * 8;

    f32x4 acc[2][2];
    #pragma unroll
    for (int i = 0; i < 2; ++i)
        #pragma unroll
        for (int j = 0; j < 2; ++j) acc[i][j] = (f32x4){0.f, 0.f, 0.f, 0.f};

    int srow = tid >> 2, sg = tid & 3;   // staging: 4 thr/row, 2 granules each

    for (int kc = 0; kc < C_; kc += 64) {
        if (kc) __syncthreads();
        {   // stage X (bf16 direct)
            const unsigned short* src = xcb + (size_t)(r0 + srow) * C_ + kc;
            unsigned short* drow = tX + srow * 64;
            #pragma unroll
            for (int i = 0; i < 2; ++i) {
                int g = sg + i * 4;
                uint4 v = *(const uint4*)(src + g * 8);
                *(uint4*)&drow[(g ^ (srow & 7)) * 8] = v;
            }
        }
        {   // stage W (f32 -> bf16)
            const float* srcw = w + ((size_t)o * H_ + h0 + srow) * C_ + kc;
            unsigned short* drow = tW + srow * 64;
            #pragma unroll
            for (int i = 0; i < 2; ++i) {
                int g = sg + i * 4;
                float4 v0 = *(const float4*)(srcw + g * 8);
                float4 v1 = *(const float4*)(srcw + g * 8 + 4);
                uint4 pk;
                pk.x = packbf2(v0.x, v0.y); pk.y = packbf2(v0.z, v0.w);
                pk.z = packbf2(v1.x, v1.y); pk.w = packbf2(v1.z, v1.w);
                *(uint4*)&drow[(g ^ (srow & 7)) * 8] = pk;
            }
        }
        __syncthreads();
        #pragma unroll
        for (int kk = 0; kk < 64; kk += 32) {
            short8 af[2], bf2[2];
            #pragma unroll
            for (int fi = 0; fi < 2; ++fi)
                af[fi] = *(const short8*)&tX[(wrow + fi * 16 + lr) * 64 + (gr0 ^ kk)];
            #pragma unroll
            for (int fj = 0; fj < 2; ++fj)
                bf2[fj] = *(const short8*)&tW[(wcol + fj * 16 + lr) * 64 + (gr0 ^ kk)];
            #pragma unroll
            for (int fi = 0; fi < 2; ++fi)
                #pragma unroll
                for (int fj = 0; fj < 2; ++fj)
                    acc[fi][fj] = __builtin_amdgcn_mfma_f32_16x16x32_bf16(
                        af[fi], bf2[fj], acc[fi][fj], 0, 0, 0);
        }
    }
    #pragma unroll
    for (int fi = 0; fi < 2; ++fi)
        #pragma unroll
        for (int rr = 0; rr < 4; ++rr) {
            int r = r0 + wrow + fi * 16 + lq * 4 + rr;
            #pragma unroll
            for (int fj = 0; fj < 2; ++fj) {
                int h = h0 + wcol + fj * 16 + lr;
                int hj = (h < HALF_) ? h : (h - HALF_);
                int sel = (h < HALF_) ? 0 : 1;
                xhh[(size_t)r * H_ + (hj >> 2) * 8 + sel * 4 + (hj & 3)] =
                    f2h(acc[fi][fj][rr] + bias[o * H_ + h]);
            }
        }
}

// ---------------- A2a: inv-freq table (fp64) ----------------
__global__ void init_invf(double* __restrict__ invf) {
    int j = threadIdx.x;
    if (j < HALF_) invf[j] = exp2(-20.0 * (double)j / 384.0);
}

// ---------------- A2b: RoPE cos/sin table, packed-f16 granules {c x4}{s x4} ----------------
__global__ void rope_table(const int* __restrict__ sp,
                           const double* __restrict__ invf,
                           unsigned short* __restrict__ csh) {
    int e = blockIdx.x * blockDim.x + threadIdx.x;  // 1024*384
    if (e >= B_ * 4 * P_ * HALF_) return;
    int j = e % HALF_;
    int r = e / HALF_;
    int s = sp[r];
    const double TWO_PI = 6.283185307179586476925286766559;
    double ang = (double)s * invf[j];
    double k = rint(ang * (1.0 / TWO_PI));
    float fr = (float)(ang - k * TWO_PI);
    float sv, cv;
    __sincosf(fr, &sv, &cv);
    int base = r * H_ + (j >> 2) * 8 + (j & 3);
    csh[base]     = f2h(cv);
    csh[base + 4] = f2h(sv);
}

// ---------------- B: junction GEMM via f16 MFMA, 2 t per block (best-measured) ----------------
// block = one (b, sign, t-pair): 1024 thr = 16 waves, each a 32x32 tile per t.
// x/cs granule loads are t-invariant -> loaded ONCE for both t tiles.
// K=768 as 12 chunks of 64 k. DOUBLE-buffered tiles [buf2][t2][side2][128x64]
// = 128KB + 12KB coefs, ONE barrier/chunk. 1 block/CU is the constrained
// optimum: R14 (2 groups, single buf) +22us; R17 (2 groups via VGPR squeeze
// to 32) spilled, +42us. VGPR floor ~95 -> caps <128 spill (R6/R7/R17).
__global__ __launch_bounds__(1024, 4) void junction_mfma(
    const unsigned short* __restrict__ xhh, const unsigned short* __restrict__ csh,
    const float* __restrict__ rpd, const float* __restrict__ rpa,
    const float* __restrict__ rnd, const float* __restrict__ rna,
    const int* __restrict__ org, const int* __restrict__ sp,
    unsigned short* __restrict__ w1) {
    __shared__ __align__(16) unsigned short smem[65536];   // 128KB tiles
    __shared__ __align__(16) unsigned short scofh[6144];   // 12KB: [t][side][sc|of][768]
    __shared__ int vD[P_], vA[P_];

    // bijective XCD swizzle (nwg = 736, %8 == 0)
    int nwg = gridDim.x;
    int orig = blockIdx.x;
    int xcd = orig & 7;
    int q = nwg >> 3, r8 = nwg & 7;
    int blk = (xcd < r8 ? xcd * (q + 1) : r8 * (q + 1) + (xcd - r8) * q) + (orig >> 3);

    int tp = blk % NT2_;
    int sign = (blk / NT2_) & 1;
    int b = blk / (2 * NT2_);
    int o = org[b];
    int t0 = 2 * tp, t1 = t0 + 1;
    int t1ok = (t1 < T_);
    int t1c = t1ok ? t1 : t0;       // clamped for coef reads
    int gd = sign * 2, ga = sign * 2 + 1;
    const float* pd = sign ? rnd : rpd;
    const float* pa = sign ? rna : rpa;
    int tid = threadIdx.x;

    // stage coefs for both t, f16, granule layout {s1 x4}{s2 x4}
    for (int e = tid; e < 6144; e += 1024) {
        int tsel = e / 3072;
        int rem = e - tsel * 3072;
        int side = rem / 1536;
        int rem2 = rem - side * 1536;
        int arr = rem2 / 768;              // 0 = scale, 1 = offset
        int e2 = rem2 - arr * 768;
        int tt = tsel ? t1c : t0;
        const float* base = (side ? pa : pd) + ((size_t)(o * 2 + arr) * T_ + tt) * H_;
        int hj = (e2 < HALF_) ? e2 : (e2 - HALF_);
        int sel = (e2 < HALF_) ? 0 : 1;
        int pos = (hj >> 2) * 8 + sel * 4 + (hj & 3);
        scofh[((tsel * 2 + side) * 2 + arr) * 768 + pos] = f2h(base[e2]);
    }
    if (tid < P_) {
        vD[tid] = sp[(b * 4 + gd) * P_ + tid] >= 0;
        vA[tid] = sp[(b * 4 + ga) * P_ + tid] >= 0;
    }
    const unsigned short* xdh = xhh + ((size_t)(b * 4 + gd) * P_) * H_;
    const unsigned short* xah = xhh + ((size_t)(b * 4 + ga) * P_) * H_;
    const unsigned short* cdh = csh + ((size_t)(b * 4 + gd) * P_) * H_;
    const unsigned short* cah = csh + ((size_t)(b * 4 + ga) * P_) * H_;

    int lane = tid & 63, wid = tid >> 6;            // wid 0..15
    int wrow = (wid >> 2) * 32, wcol = (wid & 3) * 32;
    int lr = lane & 15, lq = lane >> 4;
    int gr0 = (lq ^ (lr & 7)) * 8;

    f32x4 a0[2][2], a1[2][2];
    #pragma unroll
    for (int i = 0; i < 2; ++i)
        #pragma unroll
        for (int j = 0; j < 2; ++j) {
            a0[i][j] = (f32x4){0.f, 0.f, 0.f, 0.f};
            a1[i][j] = (f32x4){0.f, 0.f, 0.f, 0.f};
        }

    __syncthreads();          // scofh / vD / vA ready

    for (int ch = 0; ch < 12; ++ch) {
        unsigned short* bufb = smem + (ch & 1) * 32768;

        #pragma unroll
        for (int s = 0; s < 2; ++s) {
            int slot = tid + s * 1024;          // 2048 (row, gran) slots
            int row = slot >> 3, gran = slot & 7;
            int side = row >> 7, prow = row & 127;
            const unsigned short* xb = side ? xah : xdh;
            const unsigned short* cb = side ? cah : cdh;
            int off = prow * H_ + ch * 64 + gran * 8;
            uint4 xv = *(const uint4*)(xb + off);   // x1_01,x1_23,x2_01,x2_23
            uint4 cv = *(const uint4*)(cb + off);   // c_01,c_23,s_01,s_23
            int sw = prow * 64 + ((gran ^ (prow & 7)) << 3);
            int kb = (ch * 8 + gran) * 8;
            h2 cA = bch(cv.x), cB = bch(cv.y), sA = bch(cv.z), sB = bch(cv.w);
            {   // t0 build
                const unsigned short* cof = scofh + (side * 2) * 768;
                uint4 sc = *(const uint4*)(cof + kb);
                uint4 of = *(const uint4*)(cof + 768 + kb);
                h2 u1a = __builtin_elementwise_fma(bch(sc.x), bch(xv.x), bch(of.x));
                h2 u1b = __builtin_elementwise_fma(bch(sc.y), bch(xv.y), bch(of.y));
                h2 u2a = __builtin_elementwise_fma(bch(sc.z), bch(xv.z), bch(of.z));
                h2 u2b = __builtin_elementwise_fma(bch(sc.w), bch(xv.w), bch(of.w));
                uint4 wv;
                wv.x = hcb(__builtin_elementwise_fma(u1a, cA, -(u2a * sA)));
                wv.y = hcb(__builtin_elementwise_fma(u1b, cB, -(u2b * sB)));
                wv.z = hcb(__builtin_elementwise_fma(u1a, sA, u2a * cA));
                wv.w = hcb(__builtin_elementwise_fma(u1b, sB, u2b * cB));
                *(uint4*)&bufb[side * 8192 + sw] = wv;
            }
            {   // t1 build (same x/cs, different coefs)
                const unsigned short* cof = scofh + ((2 + side) * 2) * 768;
                uint4 sc = *(const uint4*)(cof + kb);
                uint4 of = *(const uint4*)(cof + 768 + kb);
                h2 u1a = __builtin_elementwise_fma(bch(sc.x), bch(xv.x), bch(of.x));
                h2 u1b = __builtin_elementwise_fma(bch(sc.y), bch(xv.y), bch(of.y));
                h2 u2a = __builtin_elementwise_fma(bch(sc.z), bch(xv.z), bch(of.z));
                h2 u2b = __builtin_elementwise_fma(bch(sc.w), bch(xv.w), bch(of.w));
                uint4 wv;
                wv.x = hcb(__builtin_elementwise_fma(u1a, cA, -(u2a * sA)));
                wv.y = hcb(__builtin_elementwise_fma(u1b, cB, -(u2b * sB)));
                wv.z = hcb(__builtin_elementwise_fma(u1a, sA, u2a * cA));
                wv.w = hcb(__builtin_elementwise_fma(u1b, sB, u2b * cB));
                *(uint4*)&bufb[16384 + side * 8192 + sw] = wv;
            }
        }
        __syncthreads();

        __builtin_amdgcn_s_setprio(1);
        {   // t0 MFMA
            const unsigned short* tD = bufb;
            const unsigned short* tA = bufb + 8192;
            #pragma unroll
            for (int kk = 0; kk < 64; kk += 32) {
                f16x8 af[2], bf2[2];
                #pragma unroll
                for (int fi = 0; fi < 2; ++fi)
                    af[fi] = *(const f16x8*)&tD[(wrow + fi * 16 + lr) * 64 + (gr0 ^ kk)];
                #pragma unroll
                for (int fj = 0; fj < 2; ++fj)
                    bf2[fj] = *(const f16x8*)&tA[(wcol + fj * 16 + lr) * 64 + (gr0 ^ kk)];
                #pragma unroll
                for (int fi = 0; fi < 2; ++fi)
                    #pragma unroll
                    for (int fj = 0; fj < 2; ++fj)
                        a0[fi][fj] = __builtin_amdgcn_mfma_f32_16x16x32_f16(
                            af[fi], bf2[fj], a0[fi][fj], 0, 0, 0);
            }
        }
        {   // t1 MFMA
            const unsigned short* tD = bufb + 16384;
            const unsigned short* tA = bufb + 24576;
            #pragma unroll
            for (int kk = 0; kk < 64; kk += 32) {
                f16x8 af[2], bf2[2];
                #pragma unroll
                for (int fi = 0; fi < 2; ++fi)
                    af[fi] = *(const f16x8*)&tD[(wrow + fi * 16 + lr) * 64 + (gr0 ^ kk)];
                #pragma unroll
                for (int fj = 0; fj < 2; ++fj)
                    bf2[fj] = *(const f16x8*)&tA[(wcol + fj * 16 + lr) * 64 + (gr0 ^ kk)];
                #pragma unroll
                for (int fi = 0; fi < 2; ++fi)
                    #pragma unroll
                    for (int fj = 0; fj < 2; ++fj)
                        a1[fi][fj] = __builtin_amdgcn_mfma_f32_16x16x32_f16(
                            af[fi], bf2[fj], a1[fi][fj], 0, 0, 0);
            }
        }
        __builtin_amdgcn_s_setprio(0);
    }

    // ---- epilogue ----
    // Every wave here passed bar(ch=11): all builds done; ch=11's mfma reads
    // buf1 [64,128KB) -> buf0 region [0,64KB) is free for staging.
    #pragma unroll
    for (int fi = 0; fi < 2; ++fi) {
        #pragma unroll
        for (int rr = 0; rr < 4; ++rr) {
            int d = wrow + fi * 16 + lq * 4 + rr;
            int vd = vD[d];
            #pragma unroll
            for (int fj = 0; fj < 2; ++fj) {
                int a = wcol + fj * 16 + lr;
                int va = vA[a];
                float x0 = a0[fi][fj][rr];
                float v0 = 0.0f;
                if (vd && va) v0 = (x0 > 15.0f) ? x0 : __logf(1.0f + __expf(x0));
                smem[d * P_ + a] = packbf1(v0);
                float x1 = a1[fi][fj][rr];
                float v1 = 0.0f;
                if (vd && va) v1 = (x1 > 15.0f) ? x1 : __logf(1.0f + __expf(x1));
                smem[16384 + d * P_ + a] = packbf1(v1);
            }
        }
    }
    __syncthreads();
    const uint4* s4 = (const uint4*)smem;
    uint4* d40 = (uint4*)(w1 + (size_t)((b * 2 + sign) * T_ + t0) * (P_ * P_));
    for (int i = tid; i < 2048; i += 1024) d40[i] = s4[i];
    if (t1ok) {
        uint4* d41 = (uint4*)(w1 + (size_t)((b * 2 + sign) * T_ + t1) * (P_ * P_));
        for (int i = tid; i < 2048; i += 1024) d41[i] = s4[2048 + i];
    }
}

// ---------------- C (ws path): fused transpose + mask (w1 in d_ws, no alias) ----------------
__global__ __launch_bounds__(256) void finalize_ws(const __hip_bfloat16* __restrict__ w1,
                                                   const int* __restrict__ sp,
                                                   float* __restrict__ pred,
                                                   float* __restrict__ mask) {
    __shared__ float tile[64 * 129];
    __shared__ float mval[P_];
    int blk = blockIdx.x;            // bs*128*6 + d*6 + tt   (3072 blocks)
    int tt = blk % 6;
    int d = (blk / 6) % P_;
    int bs = blk / (6 * P_);         // b*2+sign
    int b = bs >> 1, sign = bs & 1;
    int t0 = tt * 64;
    int tcnt = min(64, T_ - t0);
    int tid = threadIdx.x;

    const __hip_bfloat16* src = w1 + (size_t)bs * T_ * P_ * P_ + (size_t)d * P_;
    for (int e = tid; e < tcnt * P_; e += 256) {
        int i = e >> 7, a = e & 127;
        tile[i * 129 + a] = __bfloat162float(src[(size_t)(t0 + i) * P_ * P_ + a]);
    }
    if (tid < P_) {
        bool vd = sp[(b * 4 + sign * 2) * P_ + d] >= 0;
        bool va = sp[(b * 4 + sign * 2 + 1) * P_ + tid] >= 0;
        mval[tid] = (vd && va) ? 1.0f : 0.0f;
    }
    __syncthreads();
    size_t obase = ((size_t)(b * P_ + d) * P_) * TT_ + sign * T_ + t0;
    float* dstp = pred + obase;
    float* dstm = mask + obase;
    for (int e = tid; e < P_ * 64; e += 256) {
        int a = e >> 6, ii = e & 63;
        if (ii < tcnt) {
            dstp[(size_t)a * TT_ + ii] = tile[ii * 129 + a];
            dstm[(size_t)a * TT_ + ii] = mval[a];
        }
    }
}

// ---------------- C' (fallback): transpose only; w1 aliases mask half ----------------
__global__ __launch_bounds__(256) void transpose_out(const __hip_bfloat16* __restrict__ w1,
                                                     float* __restrict__ pred) {
    __shared__ float tile[64 * 129];
    int blk = blockIdx.x;
    int tt = blk % 6;
    int d = (blk / 6) % P_;
    int bs = blk / (6 * P_);
    int b = bs >> 1, sign = bs & 1;
    int t0 = tt * 64;
    int tcnt = min(64, T_ - t0);
    int tid = threadIdx.x;

    const __hip_bfloat16* src = w1 + (size_t)bs * T_ * P_ * P_ + (size_t)d * P_;
    for (int e = tid; e < tcnt * P_; e += 256) {
        int i = e >> 7, a = e & 127;
        tile[i * 129 + a] = __bfloat162float(src[(size_t)(t0 + i) * P_ * P_ + a]);
    }
    __syncthreads();
    float* dst = pred + ((size_t)(b * P_ + d) * P_) * TT_ + sign * T_ + t0;
    for (int e = tid; e < P_ * 64; e += 256) {
        int a = e >> 6, ii = e & 63;
        if (ii < tcnt) dst[(size_t)a * TT_ + ii] = tile[ii * 129 + a];
    }
}

// ---------------- D' (fallback): mask fill, MUST follow transpose_out ----------------
__global__ void mask_fill(const int* __restrict__ sp, float* __restrict__ mask) {
    int blk = blockIdx.x;
    int a = blk & 127;
    int d = (blk >> 7) & 127;
    int b = blk >> 14;
    bool vp = (sp[(b * 4 + 0) * P_ + d] >= 0) && (sp[(b * 4 + 1) * P_ + a] >= 0);
    bool vn = (sp[(b * 4 + 2) * P_ + d] >= 0) && (sp[(b * 4 + 3) * P_ + a] >= 0);
    float* dst = mask + (size_t)blk * TT_;
    for (int st = threadIdx.x; st < TT_; st += blockDim.x)
        dst[st] = (st < T_ ? vp : vn) ? 1.0f : 0.0f;
}

extern "C" void kernel_launch(void* const* d_in, const int* in_sizes, int n_in,
                              void* d_out, int out_size, void* d_ws, size_t ws_size,
                              hipStream_t stream) {
    const float* emb  = (const float*)d_in[0];
    const float* w    = (const float*)d_in[1];
    const float* bias = (const float*)d_in[2];
    const float* rpd  = (const float*)d_in[3];
    const float* rpa  = (const float*)d_in[4];
    const float* rnd  = (const float*)d_in[5];
    const float* rna  = (const float*)d_in[6];
    const int*   org  = (const int*)d_in[7];
    const int*   sp   = (const int*)d_in[8];

    float* out = (float*)d_out;
    float* ws  = (float*)d_ws;
    unsigned short* xhh = (unsigned short*)(ws + XHH_OFF);
    unsigned short* csh = (unsigned short*)(ws + CSH_OFF);
    double* invf = (double*)(ws + INVF_OFF);
    unsigned short* xcb = (unsigned short*)(ws + XCB_OFF);
    float* pred  = out;
    float* maskp = out + PRED_ELEMS;

    // w1 staging: prefer d_ws (enables fused finalize without the R12 alias
    // race); fall back to the mask half of d_out (then mask_fill must follow
    // transpose_out in stream order).
    size_t w1_bytes = (size_t)4 * T_ * P_ * P_ * 2;
    size_t need = (size_t)W1WS_OFF * 4 + w1_bytes;
    bool ws_ok = (ws_size >= need);
    unsigned short* w1 = ws_ok ? (unsigned short*)(ws + W1WS_OFF)
                               : (unsigned short*)maskp;

    init_invf<<<1, 384, 0, stream>>>(invf);
    gather_cols<<<1024, 256, 0, stream>>>(emb, sp, xcb);
    rope_table<<<1536, 256, 0, stream>>>(sp, invf, csh);
    dim3 gl(16, 12);
    logits_mfma<<<gl, 256, 0, stream>>>(xcb, w, bias, org, xhh);
    junction_mfma<<<2 * 2 * NT2_, 1024, 0, stream>>>(xhh, csh, rpd, rpa, rnd, rna, org, sp, w1);
    if (ws_ok) {
        finalize_ws<<<2 * 2 * P_ * 6, 256, 0, stream>>>((const __hip_bfloat16*)w1, sp, pred, maskp);
    } else {
        transpose_out<<<2 * 2 * P_ * 6, 256, 0, stream>>>((const __hip_bfloat16*)w1, pred);
        mask_fill<<<32768, 256, 0, stream>>>(sp, maskp);
    }
}